// Round 4
// baseline (1479.092 us; speedup 1.0000x reference)
//
#include <hip/hip_runtime.h>
#include <stdint.h>

#define NPTS 512
#define DIN  8192
#define HENC 2048
#define EMB  256
#define HDEC 2048
#define BR   128
#define ETA  2.0f
#define RTOL 1e-4f
#define ATOLC 1e-8f

__global__ void k_init(float* acc) {
    if (threadIdx.x < 4) acc[threadIdx.x] = 0.0f;
}

// ---------------- fp32 vector GEMM, 64x64 tile, BK=16 (LDS ~9.6 KB) ----------------
// EPI==0: C = (relu?)(A@B + bias) stored f32
// EPI==1: accumulate sum((X - (A@B+bias))^2) into *acc (recon never stored)
template<int RELU, int EPI>
__global__ __launch_bounds__(256) void k_gemm_f32(
    const float* __restrict__ A,     // [M,K] f32 row-major
    const float* __restrict__ B,     // [K,N] f32 row-major
    const float* __restrict__ bias,  // [N] f32
    float* __restrict__ C,           // EPI==0
    const float* __restrict__ X,     // EPI==1: [M,N] f32
    float* __restrict__ acc,         // EPI==1
    int Nn, int K)
{
    __shared__ float As[64 * 20];    // [m][k], padded stride 20
    __shared__ float Bs[16 * 68];    // [k][n], padded stride 68
    const int t = threadIdx.x;
    const int m0 = blockIdx.y * 64, n0 = blockIdx.x * 64;
    const int ti = t >> 4, tj = t & 15;
    float accm[4][4] = {{0.f}};
    const int ar = t >> 2, ac = (t & 3) * 4;    // A staging
    const int bk = t >> 4, bc = (t & 15) * 4;   // B staging

    for (int k0 = 0; k0 < K; k0 += 16) {
        *(float4*)(As + ar * 20 + ac) = *(const float4*)(A + (size_t)(m0 + ar) * K + k0 + ac);
        *(float4*)(Bs + bk * 68 + bc) = *(const float4*)(B + (size_t)(k0 + bk) * Nn + n0 + bc);
        __syncthreads();
        #pragma unroll
        for (int kk = 0; kk < 16; ++kk) {
            const float4 b = *(const float4*)(Bs + kk * 68 + tj * 4);
            #pragma unroll
            for (int i = 0; i < 4; ++i) {
                const float a = As[(ti * 4 + i) * 20 + kk];
                accm[i][0] += a * b.x; accm[i][1] += a * b.y;
                accm[i][2] += a * b.z; accm[i][3] += a * b.w;
            }
        }
        __syncthreads();
    }

    float local = 0.f;
    #pragma unroll
    for (int i = 0; i < 4; ++i) {
        const int row = m0 + ti * 4 + i;
        #pragma unroll
        for (int j = 0; j < 4; ++j) {
            const int colj = n0 + tj * 4 + j;
            float v = accm[i][j] + bias[colj];
            if (RELU) v = fmaxf(v, 0.f);
            if (EPI == 0) {
                C[(size_t)row * Nn + colj] = v;
            } else {
                const float d = X[(size_t)row * Nn + colj] - v;
                local += d * d;
            }
        }
    }
    if (EPI == 1) {
        #pragma unroll
        for (int off = 32; off; off >>= 1) local += __shfl_xor(local, off);
        if ((t & 63) == 0) atomicAdd(acc, local);
    }
}

// ---------------- row norms per branch ----------------
__global__ void k_sn(const float* __restrict__ latent, float* __restrict__ sn) {
    const int idx = blockIdx.x * blockDim.x + threadIdx.x;
    if (idx >= 1024) return;
    const int br = idx >> 9, r = idx & 511;
    const float* p = latent + (size_t)r * EMB + br * BR;
    float s = 0.f;
    for (int c = 0; c < BR; ++c) s += p[c] * p[c];
    sn[br * 512 + r] = s;
}

// ---------------- full distance matrix (Gram formula, as reference MST path) ----------------
// k-chunked transposed LDS tiles, 2x64x65 floats = 33.3 KB
__global__ __launch_bounds__(256) void k_dist(const float* __restrict__ latent,
                                              const float* __restrict__ sn,
                                              float* __restrict__ D)
{
    const int branch = blockIdx.y;
    const int ti = blockIdx.x >> 3, tj = blockIdx.x & 7;
    const int i0 = ti * 64, j0 = tj * 64;
    __shared__ float LiT[64 * 65];  // [k][row], stride 65
    __shared__ float LjT[64 * 65];
    const int t = threadIdx.x;
    const int pi = t >> 4, pj = t & 15;
    float dot[4][4] = {{0.f}};

    for (int kc = 0; kc < BR; kc += 64) {
        for (int idx = t; idx < 1024; idx += 256) {
            const int r = idx >> 4, kq = (idx & 15) * 4;
            const float4 vi = *(const float4*)(latent + (size_t)(i0 + r) * EMB + branch * BR + kc + kq);
            const float4 vj = *(const float4*)(latent + (size_t)(j0 + r) * EMB + branch * BR + kc + kq);
            LiT[(kq + 0) * 65 + r] = vi.x; LiT[(kq + 1) * 65 + r] = vi.y;
            LiT[(kq + 2) * 65 + r] = vi.z; LiT[(kq + 3) * 65 + r] = vi.w;
            LjT[(kq + 0) * 65 + r] = vj.x; LjT[(kq + 1) * 65 + r] = vj.y;
            LjT[(kq + 2) * 65 + r] = vj.z; LjT[(kq + 3) * 65 + r] = vj.w;
        }
        __syncthreads();
        for (int k = 0; k < 64; ++k) {
            float a[4], b[4];
            #pragma unroll
            for (int i = 0; i < 4; ++i) a[i] = LiT[k * 65 + pi * 4 + i];
            #pragma unroll
            for (int j = 0; j < 4; ++j) b[j] = LjT[k * 65 + pj * 4 + j];
            #pragma unroll
            for (int i = 0; i < 4; ++i)
                #pragma unroll
                for (int j = 0; j < 4; ++j) dot[i][j] += a[i] * b[j];
        }
        __syncthreads();
    }

    const float* snb = sn + branch * 512;
    float* Db = D + (size_t)branch * 512 * 512;
    #pragma unroll
    for (int i = 0; i < 4; ++i) {
        const int gi = i0 + pi * 4 + i;
        #pragma unroll
        for (int j = 0; j < 4; ++j) {
            const int gj = j0 + pj * 4 + j;
            const float d2 = snb[gi] + snb[gj] - 2.0f * dot[i][j];
            Db[(size_t)gi * 512 + gj] = sqrtf(fmaxf(d2, 0.0f));
        }
    }
}

// ---------------- Prim's MST: 1 wave per branch + L2 prewarm; emits {mst, band} ----------------
__global__ __launch_bounds__(256) void k_prim(const float* __restrict__ D,
                                              float2* __restrict__ mstb,
                                              float* __restrict__ acc)
{
    const int branch = blockIdx.x;
    const float* Db = D + (size_t)branch * 512 * 512;
    float2* mb = mstb + branch * 511;
    const int t = threadIdx.x;

    // Prewarm D into L2 (touch every cacheline)
    float s = 0.f;
    for (int i = t; i < 16384; i += 256) s += Db[(size_t)i * 16];
    if (s == -1e30f) acc[3] = s;  // never true; keeps loads alive
    __syncthreads();
    if (t >= 64) return;

    const int l = t;
    float mind[8];
    {
        const float4* rp = (const float4*)(Db + l * 8);
        float4 a = rp[0], b = rp[1];
        mind[0]=a.x; mind[1]=a.y; mind[2]=a.z; mind[3]=a.w;
        mind[4]=b.x; mind[5]=b.y; mind[6]=b.z; mind[7]=b.w;
    }
    unsigned int intree = (l == 0) ? 1u : 0u;  // bit e marks column l*8+e

    for (int it = 0; it < 511; ++it) {
        float best = 3.0e38f; int bi = 0;
        #pragma unroll
        for (int e = 0; e < 8; ++e) {
            const float v = ((intree >> e) & 1u) ? 3.0e38f : mind[e];
            if (v < best) { best = v; bi = e; }   // strict < keeps FIRST (jnp argmin)
        }
        float g = best;
        #pragma unroll
        for (int off = 32; off; off >>= 1) g = fminf(g, __shfl_xor(g, off));
        const unsigned long long msk = __ballot(best == g);
        const int src = __ffsll(msk) - 1;         // lowest lane -> lowest global index
        const int jg = src * 8 + __shfl(bi, src);
        if (l == 0) mb[it] = make_float2(g, ATOLC + RTOL * fabsf(g));
        if (l == src) intree |= (1u << (jg - src * 8));
        const float4* rp = (const float4*)(Db + (size_t)jg * 512 + l * 8);
        const float4 u0 = rp[0], u1 = rp[1];
        mind[0] = fminf(mind[0], u0.x); mind[1] = fminf(mind[1], u0.y);
        mind[2] = fminf(mind[2], u0.z); mind[3] = fminf(mind[3], u0.w);
        mind[4] = fminf(mind[4], u1.x); mind[5] = fminf(mind[5], u1.y);
        mind[6] = fminf(mind[6], u1.z); mind[7] = fminf(mind[7], u1.w);
    }
}

// ---------------- loss: pdist (diff formula) + band scan + |ETA - d| (LDS: 33.3 KB) ----------------
__global__ __launch_bounds__(256) void k_loss(const float* __restrict__ latent,
                                              const float2* __restrict__ mstb,
                                              float* __restrict__ acc)
{
    const int branch = blockIdx.y;
    int bid = blockIdx.x, ti = 0;
    while (bid >= 8 - ti) { bid -= 8 - ti; ti++; }
    const int tj = ti + bid;
    const int i0 = ti * 64, j0 = tj * 64;
    __shared__ float LiT[64 * 65];
    __shared__ float LjT[64 * 65];
    const int t = threadIdx.x;
    const int pi = t >> 4, pj = t & 15;
    float d2[16];
    #pragma unroll
    for (int p = 0; p < 16; ++p) d2[p] = 0.f;

    for (int kc = 0; kc < BR; kc += 64) {
        for (int idx = t; idx < 1024; idx += 256) {
            const int r = idx >> 4, kq = (idx & 15) * 4;
            const float4 vi = *(const float4*)(latent + (size_t)(i0 + r) * EMB + branch * BR + kc + kq);
            const float4 vj = *(const float4*)(latent + (size_t)(j0 + r) * EMB + branch * BR + kc + kq);
            LiT[(kq + 0) * 65 + r] = vi.x; LiT[(kq + 1) * 65 + r] = vi.y;
            LiT[(kq + 2) * 65 + r] = vi.z; LiT[(kq + 3) * 65 + r] = vi.w;
            LjT[(kq + 0) * 65 + r] = vj.x; LjT[(kq + 1) * 65 + r] = vj.y;
            LjT[(kq + 2) * 65 + r] = vj.z; LjT[(kq + 3) * 65 + r] = vj.w;
        }
        __syncthreads();
        for (int k = 0; k < 64; ++k) {
            float a[4], b[4];
            #pragma unroll
            for (int i = 0; i < 4; ++i) a[i] = LiT[k * 65 + pi * 4 + i];
            #pragma unroll
            for (int j = 0; j < 4; ++j) b[j] = LjT[k * 65 + pj * 4 + j];
            #pragma unroll
            for (int i = 0; i < 4; ++i)
                #pragma unroll
                for (int j = 0; j < 4; ++j) {
                    const float df = a[i] - b[j];
                    d2[i * 4 + j] += df * df;
                }
        }
        __syncthreads();
    }

    float dd[16]; int valid[16];
    #pragma unroll
    for (int i = 0; i < 4; ++i)
        #pragma unroll
        for (int j = 0; j < 4; ++j) {
            const int gi = i0 + pi * 4 + i, gj = j0 + pj * 4 + j;
            dd[i * 4 + j] = sqrtf(d2[i * 4 + j]);
            valid[i * 4 + j] = (gi < gj);
        }
    const float2* mbp = mstb + branch * 511;
    unsigned int mm = 0;
    for (int m = 0; m < 511; ++m) {
        const float2 mv = mbp[m];   // uniform -> scalar-cached load
        #pragma unroll
        for (int p = 0; p < 16; ++p)
            if (fabsf(dd[p] - mv.x) <= mv.y) mm |= (1u << p);
    }
    float sloc = 0.f;
    #pragma unroll
    for (int p = 0; p < 16; ++p)
        if (valid[p] && ((mm >> p) & 1u)) sloc += fabsf(ETA - dd[p]);
    #pragma unroll
    for (int off = 32; off; off >>= 1) sloc += __shfl_xor(sloc, off);
    if ((t & 63) == 0) atomicAdd(&acc[1], sloc);
}

__global__ void k_final(const float* __restrict__ acc, float* __restrict__ out) {
    if (threadIdx.x == 0) {
        out[0] = acc[0] / (float)((size_t)NPTS * DIN) + acc[1];  // output dtype: float32
    }
}

extern "C" void kernel_launch(void* const* d_in, const int* in_sizes, int n_in,
                              void* d_out, int out_size, void* d_ws, size_t ws_size,
                              hipStream_t stream) {
    (void)in_sizes; (void)n_in; (void)out_size; (void)ws_size;
    // Reference setup_inputs(): ALL inputs float32.
    const float* x   = (const float*)d_in[0];
    const float* We1 = (const float*)d_in[1];
    const float* be1 = (const float*)d_in[2];
    const float* We2 = (const float*)d_in[3];
    const float* be2 = (const float*)d_in[4];
    const float* Wd1 = (const float*)d_in[5];
    const float* bd1 = (const float*)d_in[6];
    const float* Wd2 = (const float*)d_in[7];
    const float* bd2 = (const float*)d_in[8];

    // ws layout (4.52 MB total, with aliasing):
    //   acc:    [0, 4096)
    //   sn:     [4096, 8192)
    //   mstb:   [8192, 16384)
    //   latent: [16384, 540672)         512*256*4 = 512 KB
    //   h1:     [540672, 4734976)       512*2048*4 = 4 MB (dead after GEMM2)
    //   Dm:     [540672, 2637824)       aliases h1 (dead after k_prim)
    //   h2:     [540672, 4734976)       aliases h1/Dm (written at GEMM3, after both dead)
    char* ws = (char*)d_ws;
    float*  acc    = (float*)(ws);
    float*  sn     = (float*)(ws + 4096);
    float2* mstb   = (float2*)(ws + 8192);
    float*  latent = (float*)(ws + 16384);
    float*  h1     = (float*)(ws + 540672);
    float*  Dm     = (float*)(ws + 540672);
    float*  h2     = (float*)(ws + 540672);

    k_init<<<1, 64, 0, stream>>>(acc);
    // encoder: h1 = relu(x@We1+b1); latent = h1@We2+b2
    k_gemm_f32<1, 0><<<dim3(HENC / 64, NPTS / 64), 256, 0, stream>>>(x, We1, be1, h1, nullptr, nullptr, HENC, DIN);
    k_gemm_f32<0, 0><<<dim3(EMB / 64, NPTS / 64), 256, 0, stream>>>(h1, We2, be2, latent, nullptr, nullptr, EMB, HENC);
    // connectivity loss (h1 dead from here; Dm aliases it)
    k_sn<<<4, 256, 0, stream>>>(latent, sn);
    k_dist<<<dim3(64, 2), 256, 0, stream>>>(latent, sn, Dm);
    k_prim<<<2, 256, 0, stream>>>(Dm, mstb, acc);
    k_loss<<<dim3(36, 2), 256, 0, stream>>>(latent, mstb, acc);
    // decoder + fused reconstruction loss (Dm dead; h2 aliases the region)
    k_gemm_f32<1, 0><<<dim3(HDEC / 64, NPTS / 64), 256, 0, stream>>>(latent, Wd1, bd1, h2, nullptr, nullptr, HDEC, EMB);
    k_gemm_f32<0, 1><<<dim3(DIN / 64, NPTS / 64), 256, 0, stream>>>(h2, Wd2, bd2, nullptr, x, acc, DIN, HDEC);
    k_final<<<1, 64, 0, stream>>>(acc, (float*)d_out);
}

// Round 5
// 1132.758 us; speedup vs baseline: 1.3057x; 1.3057x over previous
//
#include <hip/hip_runtime.h>
#include <stdint.h>

#define NPTS 512
#define DIN  8192
#define HENC 2048
#define EMB  256
#define HDEC 2048
#define BR   128
#define ETA  2.0f
#define RTOL 1e-4f
#define ATOLC 1e-8f

typedef __attribute__((ext_vector_type(8))) short bf16x8;
typedef __attribute__((ext_vector_type(4))) float f32x4;

__device__ __forceinline__ unsigned short f2bf(float f) {
    unsigned int x = __builtin_bit_cast(unsigned int, f);
    unsigned int lsb = (x >> 16) & 1u;
    x += 0x7fffu + lsb;
    return (unsigned short)(x >> 16);
}

__global__ void k_init(float* acc) {
    if (threadIdx.x < 4) acc[threadIdx.x] = 0.0f;
}

// ============ fp32 GEMM v2: 64x64 tile, BK=32, transposed-A LDS, reg double-buffer ============
// Latent path: serial-K per output -> bit-identical accumulation order to v1.
template<int RELU>
__global__ __launch_bounds__(256) void k_gemm_f32v2(
    const float* __restrict__ A,     // [M,K]
    const float* __restrict__ B,     // [K,N]
    const float* __restrict__ bias,  // [N]
    float* __restrict__ C,
    int Nn, int K)
{
    __shared__ float AT[2][32 * 68];   // [k][m] stride 68
    __shared__ float Bs[2][32 * 68];   // [k][n] stride 68
    const int t = threadIdx.x;
    const int m0 = blockIdx.y * 64, n0 = blockIdx.x * 64;
    const int ti = t >> 4, tj = t & 15;
    const int ar = t >> 2, ac = (t & 3) * 8;   // A: row, k-offset (8 wide)
    const int bk = t >> 3, bc = (t & 7) * 8;   // B: k, n-offset (8 wide)

    float accm[4][4] = {{0.f}};
    float4 ra0, ra1, rb0, rb1;

    // prologue: first tile
    ra0 = *(const float4*)(A + (size_t)(m0 + ar) * K + ac);
    ra1 = *(const float4*)(A + (size_t)(m0 + ar) * K + ac + 4);
    rb0 = *(const float4*)(B + (size_t)bk * Nn + n0 + bc);
    rb1 = *(const float4*)(B + (size_t)bk * Nn + n0 + bc + 4);
    {
        float av[8] = {ra0.x, ra0.y, ra0.z, ra0.w, ra1.x, ra1.y, ra1.z, ra1.w};
        #pragma unroll
        for (int e = 0; e < 8; ++e) AT[0][(ac + e) * 68 + ar] = av[e];
        *(float4*)(&Bs[0][bk * 68 + bc]) = rb0;
        *(float4*)(&Bs[0][bk * 68 + bc + 4]) = rb1;
    }
    __syncthreads();

    int cur = 0;
    for (int k0 = 0; k0 < K; k0 += 32) {
        const int kn = k0 + 32;
        const bool has_next = (kn < K);
        if (has_next) {
            ra0 = *(const float4*)(A + (size_t)(m0 + ar) * K + kn + ac);
            ra1 = *(const float4*)(A + (size_t)(m0 + ar) * K + kn + ac + 4);
            rb0 = *(const float4*)(B + (size_t)(kn + bk) * Nn + n0 + bc);
            rb1 = *(const float4*)(B + (size_t)(kn + bk) * Nn + n0 + bc + 4);
        }
        const float* at = AT[cur];
        const float* bs = Bs[cur];
        #pragma unroll 8
        for (int kk = 0; kk < 32; ++kk) {
            const float4 a = *(const float4*)(at + kk * 68 + ti * 4);
            const float4 b = *(const float4*)(bs + kk * 68 + tj * 4);
            accm[0][0] += a.x * b.x; accm[0][1] += a.x * b.y; accm[0][2] += a.x * b.z; accm[0][3] += a.x * b.w;
            accm[1][0] += a.y * b.x; accm[1][1] += a.y * b.y; accm[1][2] += a.y * b.z; accm[1][3] += a.y * b.w;
            accm[2][0] += a.z * b.x; accm[2][1] += a.z * b.y; accm[2][2] += a.z * b.z; accm[2][3] += a.z * b.w;
            accm[3][0] += a.w * b.x; accm[3][1] += a.w * b.y; accm[3][2] += a.w * b.z; accm[3][3] += a.w * b.w;
        }
        if (has_next) {
            __syncthreads();
            const int nxt = cur ^ 1;
            float av[8] = {ra0.x, ra0.y, ra0.z, ra0.w, ra1.x, ra1.y, ra1.z, ra1.w};
            #pragma unroll
            for (int e = 0; e < 8; ++e) AT[nxt][(ac + e) * 68 + ar] = av[e];
            *(float4*)(&Bs[nxt][bk * 68 + bc]) = rb0;
            *(float4*)(&Bs[nxt][bk * 68 + bc + 4]) = rb1;
            __syncthreads();
            cur = nxt;
        }
    }

    #pragma unroll
    for (int i = 0; i < 4; ++i) {
        const int row = m0 + ti * 4 + i;
        #pragma unroll
        for (int j = 0; j < 4; ++j) {
            const int colj = n0 + tj * 4 + j;
            float v = accm[i][j] + bias[colj];
            if (RELU) v = fmaxf(v, 0.f);
            C[(size_t)row * Nn + colj] = v;
        }
    }
}

// ============ bf16 MFMA GEMM (decoder path), 64x64 tile, BK=32 ============
// A_BF16: A is bf16 (ushort) else f32 (converted in staging). B is f32 (converted).
// EPI==0: Cb = bf16(relu(A@B + bias)); EPI==1: acc += sum((X - (A@B+bias))^2)
template<int EPI, int A_BF16>
__global__ __launch_bounds__(256) void k_gemm_bf16(
    const void* __restrict__ Araw,
    const float* __restrict__ B,
    const float* __restrict__ bias,
    unsigned short* __restrict__ Cb,
    const float* __restrict__ X,
    float* __restrict__ acc,
    int Nn, int K)
{
    __shared__ unsigned short As[64 * 40];  // [m][k] stride 40
    __shared__ unsigned short Bt[64 * 40];  // [n][k] stride 40
    const int t = threadIdx.x;
    const int w = t >> 6;
    const int l = t & 63;
    const int quad = l >> 4;
    const int r16 = l & 15;
    const int n0 = blockIdx.x * 64;
    const int m0 = blockIdx.y * 64;

    f32x4 c0 = {0,0,0,0}, c1 = {0,0,0,0}, c2 = {0,0,0,0}, c3 = {0,0,0,0};

    const int ar = t >> 2, ac = (t & 3) * 8;
    const int bk = t >> 3, bc = (t & 7) * 8;

    for (int k0 = 0; k0 < K; k0 += 32) {
        // stage A
        if (A_BF16) {
            const unsigned short* A = (const unsigned short*)Araw;
            const int4 av = *(const int4*)(A + (size_t)(m0 + ar) * K + k0 + ac);
            *(int4*)(As + ar * 40 + ac) = av;
        } else {
            const float* A = (const float*)Araw;
            const float4 a0 = *(const float4*)(A + (size_t)(m0 + ar) * K + k0 + ac);
            const float4 a1 = *(const float4*)(A + (size_t)(m0 + ar) * K + k0 + ac + 4);
            int4 packed;
            packed.x = (int)(((unsigned int)f2bf(a0.y) << 16) | f2bf(a0.x));
            packed.y = (int)(((unsigned int)f2bf(a0.w) << 16) | f2bf(a0.z));
            packed.z = (int)(((unsigned int)f2bf(a1.y) << 16) | f2bf(a1.x));
            packed.w = (int)(((unsigned int)f2bf(a1.w) << 16) | f2bf(a1.z));
            *(int4*)(As + ar * 40 + ac) = packed;
        }
        // stage B (transpose + convert)
        {
            const float4 b0 = *(const float4*)(B + (size_t)(k0 + bk) * Nn + n0 + bc);
            const float4 b1 = *(const float4*)(B + (size_t)(k0 + bk) * Nn + n0 + bc + 4);
            const float bv[8] = {b0.x, b0.y, b0.z, b0.w, b1.x, b1.y, b1.z, b1.w};
            #pragma unroll
            for (int e = 0; e < 8; ++e) Bt[(bc + e) * 40 + bk] = f2bf(bv[e]);
        }
        __syncthreads();

        bf16x8 bf = *(const bf16x8*)(Bt + (w * 16 + r16) * 40 + quad * 8);
        bf16x8 a0 = *(const bf16x8*)(As + (0  + r16) * 40 + quad * 8);
        bf16x8 a1 = *(const bf16x8*)(As + (16 + r16) * 40 + quad * 8);
        bf16x8 a2 = *(const bf16x8*)(As + (32 + r16) * 40 + quad * 8);
        bf16x8 a3 = *(const bf16x8*)(As + (48 + r16) * 40 + quad * 8);
        c0 = __builtin_amdgcn_mfma_f32_16x16x32_bf16(a0, bf, c0, 0, 0, 0);
        c1 = __builtin_amdgcn_mfma_f32_16x16x32_bf16(a1, bf, c1, 0, 0, 0);
        c2 = __builtin_amdgcn_mfma_f32_16x16x32_bf16(a2, bf, c2, 0, 0, 0);
        c3 = __builtin_amdgcn_mfma_f32_16x16x32_bf16(a3, bf, c3, 0, 0, 0);
        __syncthreads();
    }

    const int col = n0 + w * 16 + r16;
    const float bval = bias[col];
    f32x4 frags[4] = {c0, c1, c2, c3};
    float local = 0.f;
    #pragma unroll
    for (int f = 0; f < 4; ++f) {
        #pragma unroll
        for (int rg = 0; rg < 4; ++rg) {
            const int row = m0 + f * 16 + quad * 4 + rg;  // C/D: col=lane&15, row=quad*4+reg (m89)
            const float v = frags[f][rg] + bval;
            if (EPI == 0) {
                Cb[(size_t)row * Nn + col] = f2bf(fmaxf(v, 0.f));
            } else {
                const float d = X[(size_t)row * Nn + col] - v;
                local += d * d;
            }
        }
    }
    if (EPI == 1) {
        #pragma unroll
        for (int off = 32; off; off >>= 1) local += __shfl_xor(local, off);
        if (l == 0) atomicAdd(acc, local);
    }
}

// ---------------- row norms per branch ----------------
__global__ void k_sn(const float* __restrict__ latent, float* __restrict__ sn) {
    const int idx = blockIdx.x * blockDim.x + threadIdx.x;
    if (idx >= 1024) return;
    const int br = idx >> 9, r = idx & 511;
    const float* p = latent + (size_t)r * EMB + br * BR;
    float s = 0.f;
    for (int c = 0; c < BR; ++c) s += p[c] * p[c];
    sn[br * 512 + r] = s;
}

// ---------------- full distance matrix (Gram formula, as reference MST path) ----------------
__global__ __launch_bounds__(256) void k_dist(const float* __restrict__ latent,
                                              const float* __restrict__ sn,
                                              float* __restrict__ D)
{
    const int branch = blockIdx.y;
    const int ti = blockIdx.x >> 3, tj = blockIdx.x & 7;
    const int i0 = ti * 64, j0 = tj * 64;
    __shared__ float LiT[64 * 65];  // [k][row], stride 65
    __shared__ float LjT[64 * 65];
    const int t = threadIdx.x;
    const int pi = t >> 4, pj = t & 15;
    float dot[4][4] = {{0.f}};

    for (int kc = 0; kc < BR; kc += 64) {
        for (int idx = t; idx < 1024; idx += 256) {
            const int r = idx >> 4, kq = (idx & 15) * 4;
            const float4 vi = *(const float4*)(latent + (size_t)(i0 + r) * EMB + branch * BR + kc + kq);
            const float4 vj = *(const float4*)(latent + (size_t)(j0 + r) * EMB + branch * BR + kc + kq);
            LiT[(kq + 0) * 65 + r] = vi.x; LiT[(kq + 1) * 65 + r] = vi.y;
            LiT[(kq + 2) * 65 + r] = vi.z; LiT[(kq + 3) * 65 + r] = vi.w;
            LjT[(kq + 0) * 65 + r] = vj.x; LjT[(kq + 1) * 65 + r] = vj.y;
            LjT[(kq + 2) * 65 + r] = vj.z; LjT[(kq + 3) * 65 + r] = vj.w;
        }
        __syncthreads();
        for (int k = 0; k < 64; ++k) {
            float a[4], b[4];
            #pragma unroll
            for (int i = 0; i < 4; ++i) a[i] = LiT[k * 65 + pi * 4 + i];
            #pragma unroll
            for (int j = 0; j < 4; ++j) b[j] = LjT[k * 65 + pj * 4 + j];
            #pragma unroll
            for (int i = 0; i < 4; ++i)
                #pragma unroll
                for (int j = 0; j < 4; ++j) dot[i][j] += a[i] * b[j];
        }
        __syncthreads();
    }

    const float* snb = sn + branch * 512;
    float* Db = D + (size_t)branch * 512 * 512;
    #pragma unroll
    for (int i = 0; i < 4; ++i) {
        const int gi = i0 + pi * 4 + i;
        #pragma unroll
        for (int j = 0; j < 4; ++j) {
            const int gj = j0 + pj * 4 + j;
            const float d2 = snb[gi] + snb[gj] - 2.0f * dot[i][j];
            Db[(size_t)gi * 512 + gj] = sqrtf(fmaxf(d2, 0.0f));
        }
    }
}

// ---------------- Prim's MST: 1 wave per branch + L2 prewarm; emits {mst, band} ----------------
__global__ __launch_bounds__(256) void k_prim(const float* __restrict__ D,
                                              float2* __restrict__ mstb,
                                              float* __restrict__ acc)
{
    const int branch = blockIdx.x;
    const float* Db = D + (size_t)branch * 512 * 512;
    float2* mb = mstb + branch * 511;
    const int t = threadIdx.x;

    float s = 0.f;
    for (int i = t; i < 16384; i += 256) s += Db[(size_t)i * 16];
    if (s == -1e30f) acc[3] = s;  // never true; keeps prewarm loads alive
    __syncthreads();
    if (t >= 64) return;

    const int l = t;
    float mind[8];
    {
        const float4* rp = (const float4*)(Db + l * 8);
        float4 a = rp[0], b = rp[1];
        mind[0]=a.x; mind[1]=a.y; mind[2]=a.z; mind[3]=a.w;
        mind[4]=b.x; mind[5]=b.y; mind[6]=b.z; mind[7]=b.w;
    }
    unsigned int intree = (l == 0) ? 1u : 0u;

    for (int it = 0; it < 511; ++it) {
        float best = 3.0e38f; int bi = 0;
        #pragma unroll
        for (int e = 0; e < 8; ++e) {
            const float v = ((intree >> e) & 1u) ? 3.0e38f : mind[e];
            if (v < best) { best = v; bi = e; }   // strict < keeps FIRST (jnp argmin)
        }
        float g = best;
        #pragma unroll
        for (int off = 32; off; off >>= 1) g = fminf(g, __shfl_xor(g, off));
        const unsigned long long msk = __ballot(best == g);
        const int src = __ffsll(msk) - 1;
        const int jg = src * 8 + __shfl(bi, src);
        if (l == 0) mb[it] = make_float2(g, ATOLC + RTOL * fabsf(g));
        if (l == src) intree |= (1u << (jg - src * 8));
        const float4* rp = (const float4*)(Db + (size_t)jg * 512 + l * 8);
        const float4 u0 = rp[0], u1 = rp[1];
        mind[0] = fminf(mind[0], u0.x); mind[1] = fminf(mind[1], u0.y);
        mind[2] = fminf(mind[2], u0.z); mind[3] = fminf(mind[3], u0.w);
        mind[4] = fminf(mind[4], u1.x); mind[5] = fminf(mind[5], u1.y);
        mind[6] = fminf(mind[6], u1.z); mind[7] = fminf(mind[7], u1.w);
    }
}

// ---------------- loss: pdist (diff formula) + band scan + |ETA - d| ----------------
__global__ __launch_bounds__(256) void k_loss(const float* __restrict__ latent,
                                              const float2* __restrict__ mstb,
                                              float* __restrict__ acc)
{
    const int branch = blockIdx.y;
    int bid = blockIdx.x, ti = 0;
    while (bid >= 8 - ti) { bid -= 8 - ti; ti++; }
    const int tj = ti + bid;
    const int i0 = ti * 64, j0 = tj * 64;
    __shared__ float LiT[64 * 65];
    __shared__ float LjT[64 * 65];
    const int t = threadIdx.x;
    const int pi = t >> 4, pj = t & 15;
    float d2[16];
    #pragma unroll
    for (int p = 0; p < 16; ++p) d2[p] = 0.f;

    for (int kc = 0; kc < BR; kc += 64) {
        for (int idx = t; idx < 1024; idx += 256) {
            const int r = idx >> 4, kq = (idx & 15) * 4;
            const float4 vi = *(const float4*)(latent + (size_t)(i0 + r) * EMB + branch * BR + kc + kq);
            const float4 vj = *(const float4*)(latent + (size_t)(j0 + r) * EMB + branch * BR + kc + kq);
            LiT[(kq + 0) * 65 + r] = vi.x; LiT[(kq + 1) * 65 + r] = vi.y;
            LiT[(kq + 2) * 65 + r] = vi.z; LiT[(kq + 3) * 65 + r] = vi.w;
            LjT[(kq + 0) * 65 + r] = vj.x; LjT[(kq + 1) * 65 + r] = vj.y;
            LjT[(kq + 2) * 65 + r] = vj.z; LjT[(kq + 3) * 65 + r] = vj.w;
        }
        __syncthreads();
        for (int k = 0; k < 64; ++k) {
            float a[4], b[4];
            #pragma unroll
            for (int i = 0; i < 4; ++i) a[i] = LiT[k * 65 + pi * 4 + i];
            #pragma unroll
            for (int j = 0; j < 4; ++j) b[j] = LjT[k * 65 + pj * 4 + j];
            #pragma unroll
            for (int i = 0; i < 4; ++i)
                #pragma unroll
                for (int j = 0; j < 4; ++j) {
                    const float df = a[i] - b[j];
                    d2[i * 4 + j] += df * df;
                }
        }
        __syncthreads();
    }

    float dd[16]; int valid[16];
    #pragma unroll
    for (int i = 0; i < 4; ++i)
        #pragma unroll
        for (int j = 0; j < 4; ++j) {
            const int gi = i0 + pi * 4 + i, gj = j0 + pj * 4 + j;
            dd[i * 4 + j] = sqrtf(d2[i * 4 + j]);
            valid[i * 4 + j] = (gi < gj);
        }
    const float2* mbp = mstb + branch * 511;
    unsigned int mm = 0;
    for (int m = 0; m < 511; ++m) {
        const float2 mv = mbp[m];
        #pragma unroll
        for (int p = 0; p < 16; ++p)
            if (fabsf(dd[p] - mv.x) <= mv.y) mm |= (1u << p);
    }
    float sloc = 0.f;
    #pragma unroll
    for (int p = 0; p < 16; ++p)
        if (valid[p] && ((mm >> p) & 1u)) sloc += fabsf(ETA - dd[p]);
    #pragma unroll
    for (int off = 32; off; off >>= 1) sloc += __shfl_xor(sloc, off);
    if ((t & 63) == 0) atomicAdd(&acc[1], sloc);
}

__global__ void k_final(const float* __restrict__ acc, float* __restrict__ out) {
    if (threadIdx.x == 0) {
        out[0] = acc[0] / (float)((size_t)NPTS * DIN) + acc[1];
    }
}

extern "C" void kernel_launch(void* const* d_in, const int* in_sizes, int n_in,
                              void* d_out, int out_size, void* d_ws, size_t ws_size,
                              hipStream_t stream) {
    (void)in_sizes; (void)n_in; (void)out_size; (void)ws_size;
    const float* x   = (const float*)d_in[0];
    const float* We1 = (const float*)d_in[1];
    const float* be1 = (const float*)d_in[2];
    const float* We2 = (const float*)d_in[3];
    const float* be2 = (const float*)d_in[4];
    const float* Wd1 = (const float*)d_in[5];
    const float* bd1 = (const float*)d_in[6];
    const float* Wd2 = (const float*)d_in[7];
    const float* bd2 = (const float*)d_in[8];

    // ws layout (4.73 MB peak, with aliasing):
    //   acc @0, sn @4096, mstb @8192, latent @16384 (512 KB)
    //   h1 @540672 (4 MB, dead after GEMM2) / Dm aliases (dead after prim) / h2b bf16 (2 MB)
    char* ws = (char*)d_ws;
    float*          acc    = (float*)(ws);
    float*          sn     = (float*)(ws + 4096);
    float2*         mstb   = (float2*)(ws + 8192);
    float*          latent = (float*)(ws + 16384);
    float*          h1     = (float*)(ws + 540672);
    float*          Dm     = (float*)(ws + 540672);
    unsigned short* h2b    = (unsigned short*)(ws + 540672);

    k_init<<<1, 64, 0, stream>>>(acc);
    // encoder (fp32, bit-identical accumulation order)
    k_gemm_f32v2<1><<<dim3(HENC / 64, NPTS / 64), 256, 0, stream>>>(x, We1, be1, h1, HENC, DIN);
    k_gemm_f32v2<0><<<dim3(EMB / 64, NPTS / 64), 256, 0, stream>>>(h1, We2, be2, latent, EMB, HENC);
    // connectivity loss (h1 dead; Dm aliases it)
    k_sn<<<4, 256, 0, stream>>>(latent, sn);
    k_dist<<<dim3(64, 2), 256, 0, stream>>>(latent, sn, Dm);
    k_prim<<<2, 256, 0, stream>>>(Dm, mstb, acc);
    k_loss<<<dim3(36, 2), 256, 0, stream>>>(latent, mstb, acc);
    // decoder (bf16 MFMA; Dm dead, h2b aliases region) + fused MSE
    k_gemm_bf16<0, 0><<<dim3(HDEC / 64, NPTS / 64), 256, 0, stream>>>(latent, Wd1, bd1, h2b, nullptr, nullptr, HDEC, EMB);
    k_gemm_bf16<1, 1><<<dim3(DIN / 64, NPTS / 64), 256, 0, stream>>>(h2b, Wd2, bd2, nullptr, x, acc, DIN, HDEC);
    k_final<<<1, 64, 0, stream>>>(acc, (float*)d_out);
}

// Round 6
// 1104.706 us; speedup vs baseline: 1.3389x; 1.0254x over previous
//
#include <hip/hip_runtime.h>
#include <stdint.h>

#define NPTS 512
#define DIN  8192
#define HENC 2048
#define EMB  256
#define HDEC 2048
#define BR   128
#define ETA  2.0f
#define RTOL 1e-4f
#define ATOLC 1e-8f

typedef __attribute__((ext_vector_type(8))) short bf16x8;
typedef __attribute__((ext_vector_type(4))) float f32x4;

__device__ __forceinline__ unsigned short f2bf(float f) {
    unsigned int x = __builtin_bit_cast(unsigned int, f);
    unsigned int lsb = (x >> 16) & 1u;
    x += 0x7fffu + lsb;
    return (unsigned short)(x >> 16);
}

__global__ void k_init(float* acc) {
    if (threadIdx.x < 4) acc[threadIdx.x] = 0.0f;
}

// ============ bf16 MFMA GEMM, 64x64 tile, BK=32 ============
// Inputs are value-bf16-ified f32 -> f32->bf16 conversion of x/W is lossless.
// OUT==0: Cf = relu(A@B+bias) f32   (GEMM1: h1)
// OUT==1: Cb = bf16(relu(A@B+bias)) (GEMM3: h2b)
// OUT==2: acc += sum((X-(A@B+bias))^2) (GEMM4, recon never stored)
// A_BF16==1: A is bf16 ushort (h2b); else f32 converted in staging.
template<int OUT, int A_BF16>
__global__ __launch_bounds__(256) void k_mfma(
    const void* __restrict__ Araw,
    const float* __restrict__ B,
    const float* __restrict__ bias,
    float* __restrict__ Cf,
    unsigned short* __restrict__ Cb,
    const float* __restrict__ X,
    float* __restrict__ acc,
    int Nn, int K)
{
    __shared__ unsigned short As[64 * 40];  // [m][k] stride 40
    __shared__ unsigned short Bt[64 * 40];  // [n][k] stride 40
    const int t = threadIdx.x;
    const int w = t >> 6;
    const int l = t & 63;
    const int quad = l >> 4;
    const int r16 = l & 15;
    const int n0 = blockIdx.x * 64;
    const int m0 = blockIdx.y * 64;

    f32x4 c0 = {0,0,0,0}, c1 = {0,0,0,0}, c2 = {0,0,0,0}, c3 = {0,0,0,0};

    const int ar = t >> 2, ac = (t & 3) * 8;
    const int bk = t >> 3, bc = (t & 7) * 8;

    for (int k0 = 0; k0 < K; k0 += 32) {
        if (A_BF16) {
            const unsigned short* A = (const unsigned short*)Araw;
            const int4 av = *(const int4*)(A + (size_t)(m0 + ar) * K + k0 + ac);
            *(int4*)(As + ar * 40 + ac) = av;
        } else {
            const float* A = (const float*)Araw;
            const float4 a0 = *(const float4*)(A + (size_t)(m0 + ar) * K + k0 + ac);
            const float4 a1 = *(const float4*)(A + (size_t)(m0 + ar) * K + k0 + ac + 4);
            int4 packed;
            packed.x = (int)(((unsigned int)f2bf(a0.y) << 16) | f2bf(a0.x));
            packed.y = (int)(((unsigned int)f2bf(a0.w) << 16) | f2bf(a0.z));
            packed.z = (int)(((unsigned int)f2bf(a1.y) << 16) | f2bf(a1.x));
            packed.w = (int)(((unsigned int)f2bf(a1.w) << 16) | f2bf(a1.z));
            *(int4*)(As + ar * 40 + ac) = packed;
        }
        {
            const float4 b0 = *(const float4*)(B + (size_t)(k0 + bk) * Nn + n0 + bc);
            const float4 b1 = *(const float4*)(B + (size_t)(k0 + bk) * Nn + n0 + bc + 4);
            const float bv[8] = {b0.x, b0.y, b0.z, b0.w, b1.x, b1.y, b1.z, b1.w};
            #pragma unroll
            for (int e = 0; e < 8; ++e) Bt[(bc + e) * 40 + bk] = f2bf(bv[e]);
        }
        __syncthreads();

        bf16x8 bf = *(const bf16x8*)(Bt + (w * 16 + r16) * 40 + quad * 8);
        bf16x8 a0 = *(const bf16x8*)(As + (0  + r16) * 40 + quad * 8);
        bf16x8 a1 = *(const bf16x8*)(As + (16 + r16) * 40 + quad * 8);
        bf16x8 a2 = *(const bf16x8*)(As + (32 + r16) * 40 + quad * 8);
        bf16x8 a3 = *(const bf16x8*)(As + (48 + r16) * 40 + quad * 8);
        c0 = __builtin_amdgcn_mfma_f32_16x16x32_bf16(a0, bf, c0, 0, 0, 0);
        c1 = __builtin_amdgcn_mfma_f32_16x16x32_bf16(a1, bf, c1, 0, 0, 0);
        c2 = __builtin_amdgcn_mfma_f32_16x16x32_bf16(a2, bf, c2, 0, 0, 0);
        c3 = __builtin_amdgcn_mfma_f32_16x16x32_bf16(a3, bf, c3, 0, 0, 0);
        __syncthreads();
    }

    const int col = n0 + w * 16 + r16;
    const float bval = bias[col];
    f32x4 frags[4] = {c0, c1, c2, c3};
    float local = 0.f;
    #pragma unroll
    for (int f = 0; f < 4; ++f) {
        #pragma unroll
        for (int rg = 0; rg < 4; ++rg) {
            const int row = m0 + f * 16 + quad * 4 + rg;  // C/D: col=lane&15, row=quad*4+reg (m89)
            const float v = frags[f][rg] + bval;
            if (OUT == 0) {
                Cf[(size_t)row * Nn + col] = fmaxf(v, 0.f);
            } else if (OUT == 1) {
                Cb[(size_t)row * Nn + col] = f2bf(fmaxf(v, 0.f));
            } else {
                const float d = X[(size_t)row * Nn + col] - v;
                local += d * d;
            }
        }
    }
    if (OUT == 2) {
        #pragma unroll
        for (int off = 32; off; off >>= 1) local += __shfl_xor(local, off);
        if (l == 0) atomicAdd(acc, local);
    }
}

// ============ GEMM2 (latent = h1@We2+b2), fp32 VALU, 64x64 tile, in-block 2-way K-split ============
// 512 threads: sub 0 -> K[0,1024), sub 1 -> K[1024,2048); ordered add at the end
// (one extra rounding vs serial-K; latent stays fp32-exact-products path).
__global__ __launch_bounds__(512) void k_gemm2(
    const float* __restrict__ A,     // [512,2048]
    const float* __restrict__ B,     // [2048,256]
    const float* __restrict__ bias,  // [256]
    float* __restrict__ C)           // [512,256]
{
    __shared__ float AT[2][32 * 68];   // per-sub [k][m]
    __shared__ float Bs[2][32 * 68];   // per-sub [k][n]
    __shared__ float red[64 * 64];
    const int t = threadIdx.x;
    const int sub = t >> 8, tt = t & 255;
    const int m0 = blockIdx.y * 64, n0 = blockIdx.x * 64;
    const int ti = tt >> 4, tj = tt & 15;
    const int ar = tt >> 2, ac = (tt & 3) * 8;
    const int bk = tt >> 3, bc = (tt & 7) * 8;
    const int kbase = sub * 1024;
    float accm[4][4] = {{0.f}};

    for (int k0 = 0; k0 < 1024; k0 += 32) {
        const int kk0 = kbase + k0;
        const float4 a0 = *(const float4*)(A + (size_t)(m0 + ar) * HENC + kk0 + ac);
        const float4 a1 = *(const float4*)(A + (size_t)(m0 + ar) * HENC + kk0 + ac + 4);
        const float av[8] = {a0.x, a0.y, a0.z, a0.w, a1.x, a1.y, a1.z, a1.w};
        #pragma unroll
        for (int e = 0; e < 8; ++e) AT[sub][(ac + e) * 68 + ar] = av[e];
        *(float4*)(&Bs[sub][bk * 68 + bc])     = *(const float4*)(B + (size_t)(kk0 + bk) * EMB + n0 + bc);
        *(float4*)(&Bs[sub][bk * 68 + bc + 4]) = *(const float4*)(B + (size_t)(kk0 + bk) * EMB + n0 + bc + 4);
        __syncthreads();
        #pragma unroll 8
        for (int kk = 0; kk < 32; ++kk) {
            const float4 a = *(const float4*)(&AT[sub][kk * 68 + ti * 4]);
            const float4 b = *(const float4*)(&Bs[sub][kk * 68 + tj * 4]);
            accm[0][0] += a.x * b.x; accm[0][1] += a.x * b.y; accm[0][2] += a.x * b.z; accm[0][3] += a.x * b.w;
            accm[1][0] += a.y * b.x; accm[1][1] += a.y * b.y; accm[1][2] += a.y * b.z; accm[1][3] += a.y * b.w;
            accm[2][0] += a.z * b.x; accm[2][1] += a.z * b.y; accm[2][2] += a.z * b.z; accm[2][3] += a.z * b.w;
            accm[3][0] += a.w * b.x; accm[3][1] += a.w * b.y; accm[3][2] += a.w * b.z; accm[3][3] += a.w * b.w;
        }
        __syncthreads();
    }

    if (sub == 1) {
        #pragma unroll
        for (int i = 0; i < 4; ++i)
            #pragma unroll
            for (int j = 0; j < 4; ++j)
                red[(ti * 4 + i) * 64 + tj * 4 + j] = accm[i][j];
    }
    __syncthreads();
    if (sub == 0) {
        #pragma unroll
        for (int i = 0; i < 4; ++i) {
            const int row = m0 + ti * 4 + i;
            #pragma unroll
            for (int j = 0; j < 4; ++j) {
                const int colj = n0 + tj * 4 + j;
                const float v = (accm[i][j] + red[(ti * 4 + i) * 64 + tj * 4 + j]) + bias[colj];
                C[(size_t)row * EMB + colj] = v;
            }
        }
    }
}

// ---------------- row norms per branch ----------------
__global__ void k_sn(const float* __restrict__ latent, float* __restrict__ sn) {
    const int idx = blockIdx.x * blockDim.x + threadIdx.x;
    if (idx >= 1024) return;
    const int br = idx >> 9, r = idx & 511;
    const float* p = latent + (size_t)r * EMB + br * BR;
    float s = 0.f;
    for (int c = 0; c < BR; ++c) s += p[c] * p[c];
    sn[br * 512 + r] = s;
}

// ---------------- full distance matrix (Gram formula, as reference MST path) ----------------
__global__ __launch_bounds__(256) void k_dist(const float* __restrict__ latent,
                                              const float* __restrict__ sn,
                                              float* __restrict__ D)
{
    const int branch = blockIdx.y;
    const int ti = blockIdx.x >> 3, tj = blockIdx.x & 7;
    const int i0 = ti * 64, j0 = tj * 64;
    __shared__ float LiT[64 * 65];  // [k][row]
    __shared__ float LjT[64 * 65];
    const int t = threadIdx.x;
    const int pi = t >> 4, pj = t & 15;
    float dot[4][4] = {{0.f}};

    for (int kc = 0; kc < BR; kc += 64) {
        for (int idx = t; idx < 1024; idx += 256) {
            const int r = idx >> 4, kq = (idx & 15) * 4;
            const float4 vi = *(const float4*)(latent + (size_t)(i0 + r) * EMB + branch * BR + kc + kq);
            const float4 vj = *(const float4*)(latent + (size_t)(j0 + r) * EMB + branch * BR + kc + kq);
            LiT[(kq + 0) * 65 + r] = vi.x; LiT[(kq + 1) * 65 + r] = vi.y;
            LiT[(kq + 2) * 65 + r] = vi.z; LiT[(kq + 3) * 65 + r] = vi.w;
            LjT[(kq + 0) * 65 + r] = vj.x; LjT[(kq + 1) * 65 + r] = vj.y;
            LjT[(kq + 2) * 65 + r] = vj.z; LjT[(kq + 3) * 65 + r] = vj.w;
        }
        __syncthreads();
        for (int k = 0; k < 64; ++k) {
            float a[4], b[4];
            #pragma unroll
            for (int i = 0; i < 4; ++i) a[i] = LiT[k * 65 + pi * 4 + i];
            #pragma unroll
            for (int j = 0; j < 4; ++j) b[j] = LjT[k * 65 + pj * 4 + j];
            #pragma unroll
            for (int i = 0; i < 4; ++i)
                #pragma unroll
                for (int j = 0; j < 4; ++j) dot[i][j] += a[i] * b[j];
        }
        __syncthreads();
    }

    const float* snb = sn + branch * 512;
    float* Db = D + (size_t)branch * 512 * 512;
    #pragma unroll
    for (int i = 0; i < 4; ++i) {
        const int gi = i0 + pi * 4 + i;
        #pragma unroll
        for (int j = 0; j < 4; ++j) {
            const int gj = j0 + pj * 4 + j;
            const float d2 = snb[gi] + snb[gj] - 2.0f * dot[i][j];
            Db[(size_t)gi * 512 + gj] = sqrtf(fmaxf(d2, 0.0f));
        }
    }
}

// ---------------- Prim's MST: 1 wave per branch + L2 prewarm; emits {mst, band} ----------------
__global__ __launch_bounds__(256) void k_prim(const float* __restrict__ D,
                                              float2* __restrict__ mstb,
                                              float* __restrict__ acc)
{
    const int branch = blockIdx.x;
    const float* Db = D + (size_t)branch * 512 * 512;
    float2* mb = mstb + branch * 511;
    const int t = threadIdx.x;

    float s = 0.f;
    for (int i = t; i < 16384; i += 256) s += Db[(size_t)i * 16];
    if (s == -1e30f) acc[3] = s;  // never true; keeps prewarm loads alive
    __syncthreads();
    if (t >= 64) return;

    const int l = t;
    float mind[8];
    {
        const float4* rp = (const float4*)(Db + l * 8);
        float4 a = rp[0], b = rp[1];
        mind[0]=a.x; mind[1]=a.y; mind[2]=a.z; mind[3]=a.w;
        mind[4]=b.x; mind[5]=b.y; mind[6]=b.z; mind[7]=b.w;
    }
    unsigned int intree = (l == 0) ? 1u : 0u;

    for (int it = 0; it < 511; ++it) {
        float best = 3.0e38f; int bi = 0;
        #pragma unroll
        for (int e = 0; e < 8; ++e) {
            const float v = ((intree >> e) & 1u) ? 3.0e38f : mind[e];
            if (v < best) { best = v; bi = e; }   // strict < keeps FIRST (jnp argmin)
        }
        float g = best;
        #pragma unroll
        for (int off = 32; off; off >>= 1) g = fminf(g, __shfl_xor(g, off));
        const unsigned long long msk = __ballot(best == g);
        const int src = __ffsll(msk) - 1;
        const int jg = src * 8 + __shfl(bi, src);
        if (l == 0) mb[it] = make_float2(g, ATOLC + RTOL * fabsf(g));
        if (l == src) intree |= (1u << (jg - src * 8));
        const float4* rp = (const float4*)(Db + (size_t)jg * 512 + l * 8);
        const float4 u0 = rp[0], u1 = rp[1];
        mind[0] = fminf(mind[0], u0.x); mind[1] = fminf(mind[1], u0.y);
        mind[2] = fminf(mind[2], u0.z); mind[3] = fminf(mind[3], u0.w);
        mind[4] = fminf(mind[4], u1.x); mind[5] = fminf(mind[5], u1.y);
        mind[6] = fminf(mind[6], u1.z); mind[7] = fminf(mind[7], u1.w);
    }
}

// ---------------- loss: pdist (diff formula) + band scan + |ETA - d| ----------------
__global__ __launch_bounds__(256) void k_loss(const float* __restrict__ latent,
                                              const float2* __restrict__ mstb,
                                              float* __restrict__ acc)
{
    const int branch = blockIdx.y;
    int bid = blockIdx.x, ti = 0;
    while (bid >= 8 - ti) { bid -= 8 - ti; ti++; }
    const int tj = ti + bid;
    const int i0 = ti * 64, j0 = tj * 64;
    __shared__ float LiT[64 * 65];
    __shared__ float LjT[64 * 65];
    const int t = threadIdx.x;
    const int pi = t >> 4, pj = t & 15;
    float d2[16];
    #pragma unroll
    for (int p = 0; p < 16; ++p) d2[p] = 0.f;

    for (int kc = 0; kc < BR; kc += 64) {
        for (int idx = t; idx < 1024; idx += 256) {
            const int r = idx >> 4, kq = (idx & 15) * 4;
            const float4 vi = *(const float4*)(latent + (size_t)(i0 + r) * EMB + branch * BR + kc + kq);
            const float4 vj = *(const float4*)(latent + (size_t)(j0 + r) * EMB + branch * BR + kc + kq);
            LiT[(kq + 0) * 65 + r] = vi.x; LiT[(kq + 1) * 65 + r] = vi.y;
            LiT[(kq + 2) * 65 + r] = vi.z; LiT[(kq + 3) * 65 + r] = vi.w;
            LjT[(kq + 0) * 65 + r] = vj.x; LjT[(kq + 1) * 65 + r] = vj.y;
            LjT[(kq + 2) * 65 + r] = vj.z; LjT[(kq + 3) * 65 + r] = vj.w;
        }
        __syncthreads();
        for (int k = 0; k < 64; ++k) {
            float a[4], b[4];
            #pragma unroll
            for (int i = 0; i < 4; ++i) a[i] = LiT[k * 65 + pi * 4 + i];
            #pragma unroll
            for (int j = 0; j < 4; ++j) b[j] = LjT[k * 65 + pj * 4 + j];
            #pragma unroll
            for (int i = 0; i < 4; ++i)
                #pragma unroll
                for (int j = 0; j < 4; ++j) {
                    const float df = a[i] - b[j];
                    d2[i * 4 + j] += df * df;
                }
        }
        __syncthreads();
    }

    float dd[16]; int valid[16];
    #pragma unroll
    for (int i = 0; i < 4; ++i)
        #pragma unroll
        for (int j = 0; j < 4; ++j) {
            const int gi = i0 + pi * 4 + i, gj = j0 + pj * 4 + j;
            dd[i * 4 + j] = sqrtf(d2[i * 4 + j]);
            valid[i * 4 + j] = (gi < gj);
        }
    const float2* mbp = mstb + branch * 511;
    unsigned int mm = 0;
    for (int m = 0; m < 511; ++m) {
        const float2 mv = mbp[m];
        #pragma unroll
        for (int p = 0; p < 16; ++p)
            if (fabsf(dd[p] - mv.x) <= mv.y) mm |= (1u << p);
    }
    float sloc = 0.f;
    #pragma unroll
    for (int p = 0; p < 16; ++p)
        if (valid[p] && ((mm >> p) & 1u)) sloc += fabsf(ETA - dd[p]);
    #pragma unroll
    for (int off = 32; off; off >>= 1) sloc += __shfl_xor(sloc, off);
    if ((t & 63) == 0) atomicAdd(&acc[1], sloc);
}

__global__ void k_final(const float* __restrict__ acc, float* __restrict__ out) {
    if (threadIdx.x == 0) {
        out[0] = acc[0] / (float)((size_t)NPTS * DIN) + acc[1];
    }
}

extern "C" void kernel_launch(void* const* d_in, const int* in_sizes, int n_in,
                              void* d_out, int out_size, void* d_ws, size_t ws_size,
                              hipStream_t stream) {
    (void)in_sizes; (void)n_in; (void)out_size; (void)ws_size;
    const float* x   = (const float*)d_in[0];
    const float* We1 = (const float*)d_in[1];
    const float* be1 = (const float*)d_in[2];
    const float* We2 = (const float*)d_in[3];
    const float* be2 = (const float*)d_in[4];
    const float* Wd1 = (const float*)d_in[5];
    const float* bd1 = (const float*)d_in[6];
    const float* Wd2 = (const float*)d_in[7];
    const float* bd2 = (const float*)d_in[8];

    // ws layout (4.73 MB peak, aliasing):
    //   acc @0, sn @4096, mstb @8192, latent @16384 (512 KB)
    //   h1 @540672 (4 MB, dead after GEMM2) / Dm aliases (dead after prim) / h2b bf16 (2 MB)
    char* ws = (char*)d_ws;
    float*          acc    = (float*)(ws);
    float*          sn     = (float*)(ws + 4096);
    float2*         mstb   = (float2*)(ws + 8192);
    float*          latent = (float*)(ws + 16384);
    float*          h1     = (float*)(ws + 540672);
    float*          Dm     = (float*)(ws + 540672);
    unsigned short* h2b    = (unsigned short*)(ws + 540672);

    k_init<<<1, 64, 0, stream>>>(acc);
    // encoder: GEMM1 via MFMA (x/We1 values are bf16-exact -> conversion lossless)
    k_mfma<0, 0><<<dim3(HENC / 64, NPTS / 64), 256, 0, stream>>>(x, We1, be1, h1, nullptr, nullptr, nullptr, HENC, DIN);
    k_gemm2<<<dim3(EMB / 64, NPTS / 64), 512, 0, stream>>>(h1, We2, be2, latent);
    // connectivity loss (h1 dead; Dm aliases it)
    k_sn<<<4, 256, 0, stream>>>(latent, sn);
    k_dist<<<dim3(64, 2), 256, 0, stream>>>(latent, sn, Dm);
    k_prim<<<2, 256, 0, stream>>>(Dm, mstb, acc);
    k_loss<<<dim3(36, 2), 256, 0, stream>>>(latent, mstb, acc);
    // decoder (bf16 MFMA) + fused MSE
    k_mfma<1, 0><<<dim3(HDEC / 64, NPTS / 64), 256, 0, stream>>>(latent, Wd1, bd1, nullptr, h2b, nullptr, nullptr, HDEC, EMB);
    k_mfma<2, 1><<<dim3(DIN / 64, NPTS / 64), 256, 0, stream>>>(h2b, Wd2, bd2, nullptr, nullptr, x, acc, DIN, HDEC);
    k_final<<<1, 64, 0, stream>>>(acc, (float*)d_out);
}

// Round 7
// 1009.637 us; speedup vs baseline: 1.4650x; 1.0942x over previous
//
#include <hip/hip_runtime.h>
#include <stdint.h>

#define NPTS 512
#define DIN  8192
#define HENC 2048
#define EMB  256
#define HDEC 2048
#define BR   128
#define ETA  2.0f
#define RTOL 1e-4f
#define ATOLC 1e-8f

typedef __attribute__((ext_vector_type(8))) short bf16x8;
typedef __attribute__((ext_vector_type(4))) float f32x4;

__device__ __forceinline__ unsigned short f2bf(float f) {
    unsigned int x = __builtin_bit_cast(unsigned int, f);
    unsigned int lsb = (x >> 16) & 1u;
    x += 0x7fffu + lsb;
    return (unsigned short)(x >> 16);
}

__global__ void k_init(float* acc) {
    if (threadIdx.x < 4) acc[threadIdx.x] = 0.0f;
}

// ============ bf16 MFMA GEMM v2: 64x64 tile, BK=32, LDS dbuf, conflict-free B staging ============
// OUT==0: Cf = relu(A@B+bias) f32   (GEMM1: h1)
// OUT==1: Cb = bf16(relu(A@B+bias)) (GEMM3: h2b)
// OUT==2: acc += sum((X-(A@B+bias))^2) (GEMM4, recon never stored)
// A_BF16==1: A is bf16 ushort; else f32 converted in staging (values bf16-exact -> lossless).
// B LDS layout: [n][kd] dwords, dword = (bf16(k=2kd) | bf16(k=2kd+1)<<16), stride 20 dw.
//   write bank: (n4+i)*20+kp -> kp spans 16 banks, n4 adds {0,16} -> 32 banks, 2-way = free.
//   read: ds_read_b128 at n*20+quad*4 dw (16B aligned), k-order identical to old ushort layout.
template<int OUT, int A_BF16>
__global__ __launch_bounds__(256) void k_mfma(
    const void* __restrict__ Araw,
    const float* __restrict__ B,
    const float* __restrict__ bias,
    float* __restrict__ Cf,
    unsigned short* __restrict__ Cb,
    const float* __restrict__ X,
    float* __restrict__ acc,
    int Nn, int K)
{
    __shared__ unsigned short As[2][64 * 40];  // [m][k] stride 40 ush
    __shared__ unsigned int   Bd[2][64 * 20];  // [n][kd] stride 20 dw
    const int t = threadIdx.x;
    const int w = t >> 6;
    const int l = t & 63;
    const int quad = l >> 4;
    const int r16 = l & 15;
    const int n0 = blockIdx.x * 64;
    const int m0 = blockIdx.y * 64;

    const int ar = t >> 2, ac = (t & 3) * 8;     // A staging
    const int kp = t & 15, n4 = (t >> 4) * 4;    // B staging

    f32x4 c0 = {0,0,0,0}, c1 = {0,0,0,0}, c2 = {0,0,0,0}, c3 = {0,0,0,0};

    int4   aI;
    float4 aF0, aF1, bR0, bR1;

    #define LOAD_TILE(k0)                                                              \
        do {                                                                           \
            if (A_BF16) {                                                              \
                const unsigned short* A = (const unsigned short*)Araw;                 \
                aI = *(const int4*)(A + (size_t)(m0 + ar) * K + (k0) + ac);            \
            } else {                                                                   \
                const float* A = (const float*)Araw;                                   \
                aF0 = *(const float4*)(A + (size_t)(m0 + ar) * K + (k0) + ac);         \
                aF1 = *(const float4*)(A + (size_t)(m0 + ar) * K + (k0) + ac + 4);     \
            }                                                                          \
            bR0 = *(const float4*)(B + (size_t)((k0) + 2 * kp) * Nn + n0 + n4);        \
            bR1 = *(const float4*)(B + (size_t)((k0) + 2 * kp + 1) * Nn + n0 + n4);    \
        } while (0)

    #define STORE_TILE(buf)                                                            \
        do {                                                                           \
            if (A_BF16) {                                                              \
                *(int4*)(&As[buf][ar * 40 + ac]) = aI;                                 \
            } else {                                                                   \
                int4 p;                                                                \
                p.x = (int)(((unsigned)f2bf(aF0.y) << 16) | f2bf(aF0.x));              \
                p.y = (int)(((unsigned)f2bf(aF0.w) << 16) | f2bf(aF0.z));              \
                p.z = (int)(((unsigned)f2bf(aF1.y) << 16) | f2bf(aF1.x));              \
                p.w = (int)(((unsigned)f2bf(aF1.w) << 16) | f2bf(aF1.z));              \
                *(int4*)(&As[buf][ar * 40 + ac]) = p;                                  \
            }                                                                          \
            const float bl[4] = {bR0.x, bR0.y, bR0.z, bR0.w};                          \
            const float bh[4] = {bR1.x, bR1.y, bR1.z, bR1.w};                          \
            _Pragma("unroll")                                                          \
            for (int i = 0; i < 4; ++i)                                                \
                Bd[buf][(n4 + i) * 20 + kp] =                                          \
                    ((unsigned)f2bf(bh[i]) << 16) | f2bf(bl[i]);                       \
        } while (0)

    LOAD_TILE(0);
    STORE_TILE(0);
    int cur = 0;
    for (int k0 = 0; k0 < K; k0 += 32) {
        const bool hn = (k0 + 32) < K;
        if (hn) LOAD_TILE(k0 + 32);
        __syncthreads();   // buf[cur] ready; prior reads of buf[cur^1] complete
        bf16x8 bf = *(const bf16x8*)(&Bd[cur][(w * 16 + r16) * 20 + quad * 4]);
        bf16x8 a0 = *(const bf16x8*)(&As[cur][(0  + r16) * 40 + quad * 8]);
        bf16x8 a1 = *(const bf16x8*)(&As[cur][(16 + r16) * 40 + quad * 8]);
        bf16x8 a2 = *(const bf16x8*)(&As[cur][(32 + r16) * 40 + quad * 8]);
        bf16x8 a3 = *(const bf16x8*)(&As[cur][(48 + r16) * 40 + quad * 8]);
        c0 = __builtin_amdgcn_mfma_f32_16x16x32_bf16(a0, bf, c0, 0, 0, 0);
        c1 = __builtin_amdgcn_mfma_f32_16x16x32_bf16(a1, bf, c1, 0, 0, 0);
        c2 = __builtin_amdgcn_mfma_f32_16x16x32_bf16(a2, bf, c2, 0, 0, 0);
        c3 = __builtin_amdgcn_mfma_f32_16x16x32_bf16(a3, bf, c3, 0, 0, 0);
        if (hn) { STORE_TILE(cur ^ 1); cur ^= 1; }
    }
    #undef LOAD_TILE
    #undef STORE_TILE

    const int col = n0 + w * 16 + r16;
    const float bval = bias[col];
    f32x4 frags[4] = {c0, c1, c2, c3};
    float local = 0.f;
    #pragma unroll
    for (int f = 0; f < 4; ++f) {
        #pragma unroll
        for (int rg = 0; rg < 4; ++rg) {
            const int row = m0 + f * 16 + quad * 4 + rg;  // C/D: col=lane&15, row=quad*4+reg (m89)
            const float v = frags[f][rg] + bval;
            if (OUT == 0) {
                Cf[(size_t)row * Nn + col] = fmaxf(v, 0.f);
            } else if (OUT == 1) {
                Cb[(size_t)row * Nn + col] = f2bf(fmaxf(v, 0.f));
            } else {
                const float d = X[(size_t)row * Nn + col] - v;
                local += d * d;
            }
        }
    }
    if (OUT == 2) {
        #pragma unroll
        for (int off = 32; off; off >>= 1) local += __shfl_xor(local, off);
        if (l == 0) atomicAdd(acc, local);
    }
}

// ============ GEMM2 (latent = h1@We2+b2), fp32 VALU, 64x64 tile, in-block 2-way K-split ============
__global__ __launch_bounds__(512) void k_gemm2(
    const float* __restrict__ A,     // [512,2048]
    const float* __restrict__ B,     // [2048,256]
    const float* __restrict__ bias,  // [256]
    float* __restrict__ C)           // [512,256]
{
    __shared__ float AT[2][32 * 68];
    __shared__ float Bs[2][32 * 68];
    __shared__ float red[64 * 64];
    const int t = threadIdx.x;
    const int sub = t >> 8, tt = t & 255;
    const int m0 = blockIdx.y * 64, n0 = blockIdx.x * 64;
    const int ti = tt >> 4, tj = tt & 15;
    const int ar = tt >> 2, ac = (tt & 3) * 8;
    const int bk = tt >> 3, bc = (tt & 7) * 8;
    const int kbase = sub * 1024;
    float accm[4][4] = {{0.f}};

    for (int k0 = 0; k0 < 1024; k0 += 32) {
        const int kk0 = kbase + k0;
        const float4 a0 = *(const float4*)(A + (size_t)(m0 + ar) * HENC + kk0 + ac);
        const float4 a1 = *(const float4*)(A + (size_t)(m0 + ar) * HENC + kk0 + ac + 4);
        const float av[8] = {a0.x, a0.y, a0.z, a0.w, a1.x, a1.y, a1.z, a1.w};
        #pragma unroll
        for (int e = 0; e < 8; ++e) AT[sub][(ac + e) * 68 + ar] = av[e];
        *(float4*)(&Bs[sub][bk * 68 + bc])     = *(const float4*)(B + (size_t)(kk0 + bk) * EMB + n0 + bc);
        *(float4*)(&Bs[sub][bk * 68 + bc + 4]) = *(const float4*)(B + (size_t)(kk0 + bk) * EMB + n0 + bc + 4);
        __syncthreads();
        #pragma unroll 8
        for (int kk = 0; kk < 32; ++kk) {
            const float4 a = *(const float4*)(&AT[sub][kk * 68 + ti * 4]);
            const float4 b = *(const float4*)(&Bs[sub][kk * 68 + tj * 4]);
            accm[0][0] += a.x * b.x; accm[0][1] += a.x * b.y; accm[0][2] += a.x * b.z; accm[0][3] += a.x * b.w;
            accm[1][0] += a.y * b.x; accm[1][1] += a.y * b.y; accm[1][2] += a.y * b.z; accm[1][3] += a.y * b.w;
            accm[2][0] += a.z * b.x; accm[2][1] += a.z * b.y; accm[2][2] += a.z * b.z; accm[2][3] += a.z * b.w;
            accm[3][0] += a.w * b.x; accm[3][1] += a.w * b.y; accm[3][2] += a.w * b.z; accm[3][3] += a.w * b.w;
        }
        __syncthreads();
    }

    if (sub == 1) {
        #pragma unroll
        for (int i = 0; i < 4; ++i)
            #pragma unroll
            for (int j = 0; j < 4; ++j)
                red[(ti * 4 + i) * 64 + tj * 4 + j] = accm[i][j];
    }
    __syncthreads();
    if (sub == 0) {
        #pragma unroll
        for (int i = 0; i < 4; ++i) {
            const int row = m0 + ti * 4 + i;
            #pragma unroll
            for (int j = 0; j < 4; ++j) {
                const int colj = n0 + tj * 4 + j;
                const float v = (accm[i][j] + red[(ti * 4 + i) * 64 + tj * 4 + j]) + bias[colj];
                C[(size_t)row * EMB + colj] = v;
            }
        }
    }
}

// ---------------- row norms per branch ----------------
__global__ void k_sn(const float* __restrict__ latent, float* __restrict__ sn) {
    const int idx = blockIdx.x * blockDim.x + threadIdx.x;
    if (idx >= 1024) return;
    const int br = idx >> 9, r = idx & 511;
    const float* p = latent + (size_t)r * EMB + br * BR;
    float s = 0.f;
    for (int c = 0; c < BR; ++c) s += p[c] * p[c];
    sn[br * 512 + r] = s;
}

// ---------------- full distance matrix (Gram formula, as reference MST path) ----------------
__global__ __launch_bounds__(256) void k_dist(const float* __restrict__ latent,
                                              const float* __restrict__ sn,
                                              float* __restrict__ D)
{
    const int branch = blockIdx.y;
    const int ti = blockIdx.x >> 3, tj = blockIdx.x & 7;
    const int i0 = ti * 64, j0 = tj * 64;
    __shared__ float LiT[64 * 65];
    __shared__ float LjT[64 * 65];
    const int t = threadIdx.x;
    const int pi = t >> 4, pj = t & 15;
    float dot[4][4] = {{0.f}};

    for (int kc = 0; kc < BR; kc += 64) {
        for (int idx = t; idx < 1024; idx += 256) {
            const int r = idx >> 4, kq = (idx & 15) * 4;
            const float4 vi = *(const float4*)(latent + (size_t)(i0 + r) * EMB + branch * BR + kc + kq);
            const float4 vj = *(const float4*)(latent + (size_t)(j0 + r) * EMB + branch * BR + kc + kq);
            LiT[(kq + 0) * 65 + r] = vi.x; LiT[(kq + 1) * 65 + r] = vi.y;
            LiT[(kq + 2) * 65 + r] = vi.z; LiT[(kq + 3) * 65 + r] = vi.w;
            LjT[(kq + 0) * 65 + r] = vj.x; LjT[(kq + 1) * 65 + r] = vj.y;
            LjT[(kq + 2) * 65 + r] = vj.z; LjT[(kq + 3) * 65 + r] = vj.w;
        }
        __syncthreads();
        for (int k = 0; k < 64; ++k) {
            float a[4], b[4];
            #pragma unroll
            for (int i = 0; i < 4; ++i) a[i] = LiT[k * 65 + pi * 4 + i];
            #pragma unroll
            for (int j = 0; j < 4; ++j) b[j] = LjT[k * 65 + pj * 4 + j];
            #pragma unroll
            for (int i = 0; i < 4; ++i)
                #pragma unroll
                for (int j = 0; j < 4; ++j) dot[i][j] += a[i] * b[j];
        }
        __syncthreads();
    }

    const float* snb = sn + branch * 512;
    float* Db = D + (size_t)branch * 512 * 512;
    #pragma unroll
    for (int i = 0; i < 4; ++i) {
        const int gi = i0 + pi * 4 + i;
        #pragma unroll
        for (int j = 0; j < 4; ++j) {
            const int gj = j0 + pj * 4 + j;
            const float d2 = snb[gi] + snb[gj] - 2.0f * dot[i][j];
            Db[(size_t)gi * 512 + gj] = sqrtf(fmaxf(d2, 0.0f));
        }
    }
}

// ---------------- Prim's MST: 1 wave per branch + L2 prewarm; emits {mst, band} ----------------
__global__ __launch_bounds__(256) void k_prim(const float* __restrict__ D,
                                              float2* __restrict__ mstb,
                                              float* __restrict__ acc)
{
    const int branch = blockIdx.x;
    const float* Db = D + (size_t)branch * 512 * 512;
    float2* mb = mstb + branch * 511;
    const int t = threadIdx.x;

    float s = 0.f;
    for (int i = t; i < 16384; i += 256) s += Db[(size_t)i * 16];
    if (s == -1e30f) acc[3] = s;  // never true; keeps prewarm loads alive
    __syncthreads();
    if (t >= 64) return;

    const int l = t;
    float mind[8];
    {
        const float4* rp = (const float4*)(Db + l * 8);
        float4 a = rp[0], b = rp[1];
        mind[0]=a.x; mind[1]=a.y; mind[2]=a.z; mind[3]=a.w;
        mind[4]=b.x; mind[5]=b.y; mind[6]=b.z; mind[7]=b.w;
    }
    unsigned int intree = (l == 0) ? 1u : 0u;

    for (int it = 0; it < 511; ++it) {
        float best = 3.0e38f; int bi = 0;
        #pragma unroll
        for (int e = 0; e < 8; ++e) {
            const float v = ((intree >> e) & 1u) ? 3.0e38f : mind[e];
            if (v < best) { best = v; bi = e; }   // strict < keeps FIRST (jnp argmin)
        }
        float g = best;
        #pragma unroll
        for (int off = 32; off; off >>= 1) g = fminf(g, __shfl_xor(g, off));
        const unsigned long long msk = __ballot(best == g);
        const int src = __ffsll(msk) - 1;
        const int jg = src * 8 + __shfl(bi, src);
        if (l == 0) mb[it] = make_float2(g, ATOLC + RTOL * fabsf(g));
        if (l == src) intree |= (1u << (jg - src * 8));
        const float4* rp = (const float4*)(Db + (size_t)jg * 512 + l * 8);
        const float4 u0 = rp[0], u1 = rp[1];
        mind[0] = fminf(mind[0], u0.x); mind[1] = fminf(mind[1], u0.y);
        mind[2] = fminf(mind[2], u0.z); mind[3] = fminf(mind[3], u0.w);
        mind[4] = fminf(mind[4], u1.x); mind[5] = fminf(mind[5], u1.y);
        mind[6] = fminf(mind[6], u1.z); mind[7] = fminf(mind[7], u1.w);
    }
}

// ---------------- loss: pdist (diff formula) + band scan + |ETA - d| ----------------
__global__ __launch_bounds__(256) void k_loss(const float* __restrict__ latent,
                                              const float2* __restrict__ mstb,
                                              float* __restrict__ acc)
{
    const int branch = blockIdx.y;
    int bid = blockIdx.x, ti = 0;
    while (bid >= 8 - ti) { bid -= 8 - ti; ti++; }
    const int tj = ti + bid;
    const int i0 = ti * 64, j0 = tj * 64;
    __shared__ float LiT[64 * 65];
    __shared__ float LjT[64 * 65];
    const int t = threadIdx.x;
    const int pi = t >> 4, pj = t & 15;
    float d2[16];
    #pragma unroll
    for (int p = 0; p < 16; ++p) d2[p] = 0.f;

    for (int kc = 0; kc < BR; kc += 64) {
        for (int idx = t; idx < 1024; idx += 256) {
            const int r = idx >> 4, kq = (idx & 15) * 4;
            const float4 vi = *(const float4*)(latent + (size_t)(i0 + r) * EMB + branch * BR + kc + kq);
            const float4 vj = *(const float4*)(latent + (size_t)(j0 + r) * EMB + branch * BR + kc + kq);
            LiT[(kq + 0) * 65 + r] = vi.x; LiT[(kq + 1) * 65 + r] = vi.y;
            LiT[(kq + 2) * 65 + r] = vi.z; LiT[(kq + 3) * 65 + r] = vi.w;
            LjT[(kq + 0) * 65 + r] = vj.x; LjT[(kq + 1) * 65 + r] = vj.y;
            LjT[(kq + 2) * 65 + r] = vj.z; LjT[(kq + 3) * 65 + r] = vj.w;
        }
        __syncthreads();
        for (int k = 0; k < 64; ++k) {
            float a[4], b[4];
            #pragma unroll
            for (int i = 0; i < 4; ++i) a[i] = LiT[k * 65 + pi * 4 + i];
            #pragma unroll
            for (int j = 0; j < 4; ++j) b[j] = LjT[k * 65 + pj * 4 + j];
            #pragma unroll
            for (int i = 0; i < 4; ++i)
                #pragma unroll
                for (int j = 0; j < 4; ++j) {
                    const float df = a[i] - b[j];
                    d2[i * 4 + j] += df * df;
                }
        }
        __syncthreads();
    }

    float dd[16]; int valid[16];
    #pragma unroll
    for (int i = 0; i < 4; ++i)
        #pragma unroll
        for (int j = 0; j < 4; ++j) {
            const int gi = i0 + pi * 4 + i, gj = j0 + pj * 4 + j;
            dd[i * 4 + j] = sqrtf(d2[i * 4 + j]);
            valid[i * 4 + j] = (gi < gj);
        }
    const float2* mbp = mstb + branch * 511;
    unsigned int mm = 0;
    for (int m = 0; m < 511; ++m) {
        const float2 mv = mbp[m];
        #pragma unroll
        for (int p = 0; p < 16; ++p)
            if (fabsf(dd[p] - mv.x) <= mv.y) mm |= (1u << p);
    }
    float sloc = 0.f;
    #pragma unroll
    for (int p = 0; p < 16; ++p)
        if (valid[p] && ((mm >> p) & 1u)) sloc += fabsf(ETA - dd[p]);
    #pragma unroll
    for (int off = 32; off; off >>= 1) sloc += __shfl_xor(sloc, off);
    if ((t & 63) == 0) atomicAdd(&acc[1], sloc);
}

__global__ void k_final(const float* __restrict__ acc, float* __restrict__ out) {
    if (threadIdx.x == 0) {
        out[0] = acc[0] / (float)((size_t)NPTS * DIN) + acc[1];
    }
}

extern "C" void kernel_launch(void* const* d_in, const int* in_sizes, int n_in,
                              void* d_out, int out_size, void* d_ws, size_t ws_size,
                              hipStream_t stream) {
    (void)in_sizes; (void)n_in; (void)out_size; (void)ws_size;
    const float* x   = (const float*)d_in[0];
    const float* We1 = (const float*)d_in[1];
    const float* be1 = (const float*)d_in[2];
    const float* We2 = (const float*)d_in[3];
    const float* be2 = (const float*)d_in[4];
    const float* Wd1 = (const float*)d_in[5];
    const float* bd1 = (const float*)d_in[6];
    const float* Wd2 = (const float*)d_in[7];
    const float* bd2 = (const float*)d_in[8];

    // ws layout (4.73 MB peak, aliasing):
    //   acc @0, sn @4096, mstb @8192, latent @16384 (512 KB)
    //   h1 @540672 (4 MB, dead after GEMM2) / Dm aliases (dead after prim) / h2b bf16 (2 MB)
    char* ws = (char*)d_ws;
    float*          acc    = (float*)(ws);
    float*          sn     = (float*)(ws + 4096);
    float2*         mstb   = (float2*)(ws + 8192);
    float*          latent = (float*)(ws + 16384);
    float*          h1     = (float*)(ws + 540672);
    float*          Dm     = (float*)(ws + 540672);
    unsigned short* h2b    = (unsigned short*)(ws + 540672);

    k_init<<<1, 64, 0, stream>>>(acc);
    // encoder: GEMM1 via MFMA (x/We1 values bf16-exact -> lossless conversion)
    k_mfma<0, 0><<<dim3(HENC / 64, NPTS / 64), 256, 0, stream>>>(x, We1, be1, h1, nullptr, nullptr, nullptr, HENC, DIN);
    k_gemm2<<<dim3(EMB / 64, NPTS / 64), 512, 0, stream>>>(h1, We2, be2, latent);
    // connectivity loss (h1 dead; Dm aliases it)
    k_sn<<<4, 256, 0, stream>>>(latent, sn);
    k_dist<<<dim3(64, 2), 256, 0, stream>>>(latent, sn, Dm);
    k_prim<<<2, 256, 0, stream>>>(Dm, mstb, acc);
    k_loss<<<dim3(36, 2), 256, 0, stream>>>(latent, mstb, acc);
    // decoder (bf16 MFMA) + fused MSE
    k_mfma<1, 0><<<dim3(HDEC / 64, NPTS / 64), 256, 0, stream>>>(latent, Wd1, bd1, nullptr, h2b, nullptr, nullptr, HDEC, EMB);
    k_mfma<2, 1><<<dim3(DIN / 64, NPTS / 64), 256, 0, stream>>>(h2b, Wd2, bd2, nullptr, nullptr, x, acc, DIN, HDEC);
    k_final<<<1, 64, 0, stream>>>(acc, (float*)d_out);
}